// Round 1
// baseline (58.361 us; speedup 1.0000x reference)
//
#include <hip/hip_runtime.h>

#define Sdim 7
#define Bnum 2
#define Cnum 20
#define Tnum 16
#define NCH  30            // Bnum*5 + Cnum
#define NCELLS (Sdim*Sdim) // 49
#define NCONF (NCELLS*Bnum)// 98
#define LCf 5.0f
#define LNf 0.5f

__global__ __launch_bounds__(128) void yolo_loss_kernel(
    const float* __restrict__ outputs,
    const float* __restrict__ boxes,
    const int*   __restrict__ labels,
    float*       __restrict__ per_img)
{
    const int n   = blockIdx.x;
    const int tid = threadIdx.x;

    __shared__ float s_out[NCELLS * NCH];  // 1470 floats
    __shared__ int   s_mask[NCONF];        // 98 flags
    __shared__ float s_red[6];

    const float* op = outputs + (size_t)n * (NCELLS * NCH);
    for (int i = tid; i < NCELLS * NCH; i += 128) s_out[i] = op[i];
    if (tid < NCONF) s_mask[tid] = 0;
    __syncthreads();

    float tl = 0.0f;
    if (tid < Tnum) {
        const float* bxp = boxes + ((size_t)n * Tnum + tid) * 4;
        float tx = bxp[0], ty = bxp[1], tw = bxp[2], th = bxp[3];

        float fx = tx * (float)Sdim;
        float fy = ty * (float)Sdim;
        int gxi = (int)fx; if (gxi < 0) gxi = 0; if (gxi > Sdim - 1) gxi = Sdim - 1;
        int gyi = (int)fy; if (gyi < 0) gyi = 0; if (gyi > Sdim - 1) gyi = Sdim - 1;
        float offx = fx - (float)gxi;
        float offy = fy - (float)gyi;

        const float* cell = s_out + (gyi * Sdim + gxi) * NCH;

        // target box corners (b1)
        float x1a = tx - tw * 0.5f, y1a = ty - th * 0.5f;
        float x2a = tx + tw * 0.5f, y2a = ty + th * 0.5f;
        float areaA = tw * th;

        float ious[2], pxv[2], pyv[2], pwv[2], phv[2], cfv[2];
        #pragma unroll
        for (int b = 0; b < 2; ++b) {
            float rx = cell[b * 5 + 0], ry = cell[b * 5 + 1];
            float pw = cell[b * 5 + 2], ph = cell[b * 5 + 3];
            float px = (rx + (float)gxi) * (1.0f / 7.0f);
            float py = (ry + (float)gyi) * (1.0f / 7.0f);
            pxv[b] = px; pyv[b] = py; pwv[b] = pw; phv[b] = ph;
            cfv[b] = cell[b * 5 + 4];

            float x1b = px - pw * 0.5f, y1b = py - ph * 0.5f;
            float x2b = px + pw * 0.5f, y2b = py + ph * 0.5f;
            float iw = fmaxf(fminf(x2a, x2b) - fmaxf(x1a, x1b), 0.0f);
            float ih = fmaxf(fminf(y2a, y2b) - fmaxf(y1a, y1b), 0.0f);
            float inter = iw * ih;
            float uni = areaA + pw * ph - inter;
            ious[b] = inter / fmaxf(uni, 1e-10f);
        }
        // reference: best = B-1 - argmax(ious[::-1])  -> ties pick the LAST box
        int best = (ious[1] >= ious[0]) ? 1 : 0;
        s_mask[(gyi * Sdim + gxi) * Bnum + best] = 1; // same-value race is benign

        const float eps = 1e-6f;
        float dx = pxv[best] - offx;
        float dy = pyv[best] - offy;
        float dw = sqrtf(fmaxf(pwv[best], eps)) - sqrtf(fmaxf(tw, eps));
        float dh = sqrtf(fmaxf(phv[best], eps)) - sqrtf(fmaxf(th, eps));
        float box_l = dx * dx + dy * dy + dw * dw + dh * dh;
        float obj_l = (cfv[best] - 1.0f) * (cfv[best] - 1.0f);

        // class loss: softmax over 20 logits vs one-hot
        const float* cl = cell + Bnum * 5;
        float m = cl[0];
        #pragma unroll
        for (int c = 1; c < Cnum; ++c) m = fmaxf(m, cl[c]);
        float ev[Cnum];
        float esum = 0.0f;
        #pragma unroll
        for (int c = 0; c < Cnum; ++c) { ev[c] = expf(cl[c] - m); esum += ev[c]; }
        int lab = labels[(size_t)n * Tnum + tid] - 1;
        float cls_l = 0.0f;
        #pragma unroll
        for (int c = 0; c < Cnum; ++c) {
            float p = ev[c] / esum;
            float o = (c == lab) ? 1.0f : 0.0f;
            float d = p - o;
            cls_l += d * d;
        }
        tl = LCf * box_l + obj_l + cls_l;
    }
    __syncthreads();

    // no-obj: sum conf^2 over unmarked slots, and count them
    float ns = 0.0f, ncnt = 0.0f;
    if (tid < NCONF) {
        int cellIdx = tid >> 1, b = tid & 1;
        if (!s_mask[tid]) {
            float c = s_out[cellIdx * NCH + b * 5 + 4];
            ns = c * c;
            ncnt = 1.0f;
        }
    }

    // block reduce (2 waves of 64)
    float v0 = tl, v1 = ns, v2 = ncnt;
    for (int off = 32; off > 0; off >>= 1) {
        v0 += __shfl_down(v0, off);
        v1 += __shfl_down(v1, off);
        v2 += __shfl_down(v2, off);
    }
    if ((tid & 63) == 0) {
        int w = tid >> 6;
        s_red[w * 3 + 0] = v0;
        s_red[w * 3 + 1] = v1;
        s_red[w * 3 + 2] = v2;
    }
    __syncthreads();
    if (tid == 0) {
        float tl_t  = s_red[0] + s_red[3];
        float ns_t  = s_red[1] + s_red[4];
        float cnt_t = s_red[2] + s_red[5];
        per_img[n] = tl_t + LNf * ns_t / cnt_t;
    }
}

__global__ __launch_bounds__(256) void reduce_mean_kernel(
    const float* __restrict__ per_img, float* __restrict__ out, int N)
{
    __shared__ double sd[256];
    double acc = 0.0;
    for (int i = threadIdx.x; i < N; i += 256) acc += (double)per_img[i];
    sd[threadIdx.x] = acc;
    __syncthreads();
    for (int s = 128; s > 0; s >>= 1) {
        if ((int)threadIdx.x < s) sd[threadIdx.x] += sd[threadIdx.x + s];
        __syncthreads();
    }
    if (threadIdx.x == 0) out[0] = (float)(sd[0] / (double)N);
}

extern "C" void kernel_launch(void* const* d_in, const int* in_sizes, int n_in,
                              void* d_out, int out_size, void* d_ws, size_t ws_size,
                              hipStream_t stream) {
    const float* outputs = (const float*)d_in[0];
    const float* boxes   = (const float*)d_in[1];
    const int*   labels  = (const int*)d_in[2];
    float* out = (float*)d_out;

    const int N = in_sizes[0] / (NCELLS * NCH); // 16384
    float* per_img = (float*)d_ws;              // N floats of scratch

    yolo_loss_kernel<<<N, 128, 0, stream>>>(outputs, boxes, labels, per_img);
    reduce_mean_kernel<<<1, 256, 0, stream>>>(per_img, out, N);
}

// Round 3
// 35.981 us; speedup vs baseline: 1.6220x; 1.6220x over previous
//
#include <hip/hip_runtime.h>

#define Sdim 7
#define Bnum 2
#define Cnum 20
#define Tnum 16
#define NCH  30            // Bnum*5 + Cnum
#define NCELLS (Sdim*Sdim) // 49
#define NCONF (NCELLS*Bnum)// 98
#define IMGF (NCELLS*NCH)  // 1470 floats per image
#define IPB  4             // images per block
#define LCf 5.0f
#define LNf 0.5f

__global__ __launch_bounds__(256) void yolo_loss_kernel(
    const float* __restrict__ outputs,
    const float* __restrict__ boxes,
    const int*   __restrict__ labels,
    float*       __restrict__ per_img)
{
    const int tid = threadIdx.x;
    const int n0  = blockIdx.x * IPB;

    __shared__ float         s_all[IPB * IMGF];   // 23520 B
    __shared__ unsigned char s_mask[IPB * NCONF]; // 392 B

    // ---- stage 4 images with exact float4 loads (4*1470 floats = 1470 float4) ----
    const float4* src4 = reinterpret_cast<const float4*>(outputs + (size_t)n0 * IMGF);
    float4* dst4 = reinterpret_cast<float4*>(s_all);
    #pragma unroll
    for (int k = 0; k < 6; ++k) {
        int j = tid + k * 256;
        if (j < (IPB * IMGF) / 4) dst4[j] = src4[j];
    }
    // clear ALL 392 mask bytes (bug in prev round: only first 256 were cleared)
    for (int i = tid; i < IPB * NCONF; i += 256) s_mask[i] = 0;
    __syncthreads();

    const int wave = tid >> 6;      // one wave per image
    const int lane = tid & 63;
    const int n    = n0 + wave;
    const float* simg = s_all + wave * IMGF;
    unsigned char* smask = s_mask + wave * NCONF;

    float tl = 0.0f;
    if (lane < Tnum) {
        const float4 bx4 = reinterpret_cast<const float4*>(boxes)[(size_t)n * Tnum + lane];
        float tx = bx4.x, ty = bx4.y, tw = bx4.z, th = bx4.w;

        float fx = tx * (float)Sdim;
        float fy = ty * (float)Sdim;
        int gxi = (int)fx;
        int gyi = (int)fy;
        float offx = fx - (float)gxi;
        float offy = fy - (float)gyi;

        const float* cell = simg + (gyi * Sdim + gxi) * NCH;

        float x1a = tx - tw * 0.5f, y1a = ty - th * 0.5f;
        float x2a = tx + tw * 0.5f, y2a = ty + th * 0.5f;
        float areaA = tw * th;

        float ious[2], pxv[2], pyv[2], pwv[2], phv[2], cfv[2];
        #pragma unroll
        for (int b = 0; b < 2; ++b) {
            float rx = cell[b * 5 + 0], ry = cell[b * 5 + 1];
            float pw = cell[b * 5 + 2], ph = cell[b * 5 + 3];
            float px = (rx + (float)gxi) * (1.0f / 7.0f);
            float py = (ry + (float)gyi) * (1.0f / 7.0f);
            pxv[b] = px; pyv[b] = py; pwv[b] = pw; phv[b] = ph;
            cfv[b] = cell[b * 5 + 4];

            float x1b = px - pw * 0.5f, y1b = py - ph * 0.5f;
            float x2b = px + pw * 0.5f, y2b = py + ph * 0.5f;
            float iw = fmaxf(fminf(x2a, x2b) - fmaxf(x1a, x1b), 0.0f);
            float ih = fmaxf(fminf(y2a, y2b) - fmaxf(y1a, y1b), 0.0f);
            float inter = iw * ih;
            float uni = areaA + pw * ph - inter;
            ious[b] = inter / fmaxf(uni, 1e-10f);
        }
        // best = B-1 - argmax(ious[::-1]) -> ties pick box 1
        int best = (ious[1] >= ious[0]) ? 1 : 0;
        smask[(gyi * Sdim + gxi) * Bnum + best] = 1; // same-value races benign

        const float eps = 1e-6f;
        float dx = pxv[best] - offx;
        float dy = pyv[best] - offy;
        float dw = sqrtf(fmaxf(pwv[best], eps)) - sqrtf(fmaxf(tw, eps));
        float dh = sqrtf(fmaxf(phv[best], eps)) - sqrtf(fmaxf(th, eps));
        float box_l = dx * dx + dy * dy + dw * dw + dh * dh;
        float obj_l = (cfv[best] - 1.0f) * (cfv[best] - 1.0f);

        // class loss: softmax over 20 logits vs one-hot
        const float* cl = cell + Bnum * 5;
        float m = cl[0];
        #pragma unroll
        for (int c = 1; c < Cnum; ++c) m = fmaxf(m, cl[c]);
        float ev[Cnum];
        float esum = 0.0f;
        #pragma unroll
        for (int c = 0; c < Cnum; ++c) { ev[c] = expf(cl[c] - m); esum += ev[c]; }
        int lab = labels[(size_t)n * Tnum + lane] - 1;
        float cls_l = 0.0f;
        #pragma unroll
        for (int c = 0; c < Cnum; ++c) {
            float p = ev[c] / esum;
            float o = (c == lab) ? 1.0f : 0.0f;
            float d = p - o;
            cls_l += d * d;
        }
        tl = LCf * box_l + obj_l + cls_l;
    }
    __syncthreads(); // mask writes visible before no-obj pass

    // ---- no-obj: conf^2 over unmarked slots + count (98 slots, 2 wave-iters) ----
    float ns = 0.0f, ncnt = 0.0f;
    #pragma unroll
    for (int it = 0; it < 2; ++it) {
        int slot = lane + it * 64;
        if (slot < NCONF && !smask[slot]) {
            int c = slot >> 1, b = slot & 1;
            float cf = simg[c * NCH + b * 5 + 4];
            ns += cf * cf;
            ncnt += 1.0f;
        }
    }

    // ---- 64-lane reduce ----
    float v0 = tl, v1 = ns, v2 = ncnt;
    #pragma unroll
    for (int off = 32; off > 0; off >>= 1) {
        v0 += __shfl_xor(v0, off);
        v1 += __shfl_xor(v1, off);
        v2 += __shfl_xor(v2, off);
    }
    if (lane == 0) per_img[n] = v0 + LNf * v1 / v2;
}

__global__ __launch_bounds__(1024) void reduce_mean_kernel(
    const float* __restrict__ per_img, float* __restrict__ out, int N)
{
    __shared__ double sd[1024];
    double acc = 0.0;
    const float4* p4 = reinterpret_cast<const float4*>(per_img);
    const int n4 = N / 4;
    for (int i = threadIdx.x; i < n4; i += 1024) {
        float4 v = p4[i];
        acc += (double)v.x + (double)v.y + (double)v.z + (double)v.w;
    }
    sd[threadIdx.x] = acc;
    __syncthreads();
    for (int s = 512; s > 0; s >>= 1) {
        if ((int)threadIdx.x < s) sd[threadIdx.x] += sd[threadIdx.x + s];
        __syncthreads();
    }
    if (threadIdx.x == 0) out[0] = (float)(sd[0] / (double)N);
}

extern "C" void kernel_launch(void* const* d_in, const int* in_sizes, int n_in,
                              void* d_out, int out_size, void* d_ws, size_t ws_size,
                              hipStream_t stream) {
    const float* outputs = (const float*)d_in[0];
    const float* boxes   = (const float*)d_in[1];
    const int*   labels  = (const int*)d_in[2];
    float* out = (float*)d_out;

    const int N = in_sizes[0] / IMGF; // 16384
    float* per_img = (float*)d_ws;    // N floats of scratch

    yolo_loss_kernel<<<N / IPB, 256, 0, stream>>>(outputs, boxes, labels, per_img);
    reduce_mean_kernel<<<1, 1024, 0, stream>>>(per_img, out, N);
}

// Round 4
// 25.276 us; speedup vs baseline: 2.3090x; 1.4236x over previous
//
#include <hip/hip_runtime.h>

#define Cnum 20
#define NCH  30             // 2*5 + 20
#define NCELLS 49
#define NCONF 98
#define IMGF 1470           // 49*30 floats per image
#define IPB  4              // images per block (one wave each)
#define LCf 5.0f
#define LNf 0.5f

__global__ __launch_bounds__(256) void yolo_loss_kernel(
    const float* __restrict__ outputs,
    const float* __restrict__ boxes,
    const int*   __restrict__ labels,
    float*       __restrict__ block_sum)
{
    const int tid  = threadIdx.x;
    const int wave = tid >> 6;
    const int lane = tid & 63;
    const int n0   = blockIdx.x * IPB;

    __shared__ float s_all[IPB * IMGF];  // 23520 B
    __shared__ float s_tri[IPB][3];      // {tl, marked_sum, marked_cnt}
    __shared__ float s_pb[IPB];

    // ---- stage 4 images straight into LDS: 1470 float4, width-16 global_load_lds ----
    const float* gsrc = outputs + (size_t)n0 * IMGF;
    #pragma unroll
    for (int k = 0; k < 6; ++k) {
        int j = tid + k * 256;                       // float4 index
        if (j < (IPB * IMGF) / 4) {                  // 1470
            __builtin_amdgcn_global_load_lds(
                (const __attribute__((address_space(1))) void*)(gsrc + (size_t)j * 4),
                (__attribute__((address_space(3))) void*)((char*)s_all + (size_t)(k * 256 + wave * 64) * 16),
                16, 0, 0);
        }
    }
    __syncthreads();

    // ---- every wave: sum ALL 98 conf^2 of its own image (mask-free) ----
    const float* simgw = s_all + wave * IMGF;
    float ns;
    {
        int c = lane >> 1, b = lane & 1;             // slots 0..63
        float cf = simgw[c * NCH + b * 5 + 4];
        ns = cf * cf;
        int s2 = lane + 64;                          // slots 64..97
        if (s2 < NCONF) {
            c = s2 >> 1; b = s2 & 1;
            cf = simgw[c * NCH + b * 5 + 4];
            ns += cf * cf;
        }
    }
    #pragma unroll
    for (int off = 32; off > 0; off >>= 1) ns += __shfl_xor(ns, off);

    // ---- wave 0: all 64 targets (4 images x 16), all lanes active ----
    if (wave == 0) {
        const int img   = lane >> 4;
        const int myidx = lane & 15;
        const int gbase = lane & 48;
        const float* simg = s_all + img * IMGF;

        const float4 bx = reinterpret_cast<const float4*>(boxes)[(size_t)n0 * 16 + lane];
        const int lab = labels[(size_t)n0 * 16 + lane] - 1;
        float tx = bx.x, ty = bx.y, tw = bx.z, th = bx.w;

        float fx = tx * 7.0f, fy = ty * 7.0f;
        int gxi = (int)fx, gyi = (int)fy;
        float offx = fx - (float)gxi;
        float offy = fy - (float)gyi;

        const float* cell = simg + (gyi * 7 + gxi) * NCH;

        float x1a = tx - tw * 0.5f, y1a = ty - th * 0.5f;
        float x2a = tx + tw * 0.5f, y2a = ty + th * 0.5f;
        float areaA = tw * th;

        float ious[2], pxv[2], pyv[2], pwv[2], phv[2], cfv[2];
        #pragma unroll
        for (int b = 0; b < 2; ++b) {
            float rx = cell[b * 5 + 0], ry = cell[b * 5 + 1];
            float pw = cell[b * 5 + 2], ph = cell[b * 5 + 3];
            float px = (rx + (float)gxi) * (1.0f / 7.0f);
            float py = (ry + (float)gyi) * (1.0f / 7.0f);
            pxv[b] = px; pyv[b] = py; pwv[b] = pw; phv[b] = ph;
            cfv[b] = cell[b * 5 + 4];

            float x1b = px - pw * 0.5f, y1b = py - ph * 0.5f;
            float x2b = px + pw * 0.5f, y2b = py + ph * 0.5f;
            float iw = fmaxf(fminf(x2a, x2b) - fmaxf(x1a, x1b), 0.0f);
            float ih = fmaxf(fminf(y2a, y2b) - fmaxf(y1a, y1b), 0.0f);
            float inter = iw * ih;
            float uni = areaA + pw * ph - inter;
            ious[b] = inter / fmaxf(uni, 1e-10f);
        }
        int best = (ious[1] >= ious[0]) ? 1 : 0;     // ties -> last box (ref semantics)

        // in-register distinct-marked-slot bookkeeping (replaces s_mask)
        int s = (gyi * 7 + gxi) * 2 + best;
        float cfm = best ? cfv[1] : cfv[0];
        bool first = true;
        #pragma unroll
        for (int j = 0; j < 15; ++j) {
            int sj = __shfl(s, gbase + j);
            if (j < myidx && sj == s) first = false;
        }
        float msum = first ? cfm * cfm : 0.0f;
        float mcnt = first ? 1.0f : 0.0f;

        const float eps = 1e-6f;
        float dx = (best ? pxv[1] : pxv[0]) - offx;
        float dy = (best ? pyv[1] : pyv[0]) - offy;
        float bw = best ? pwv[1] : pwv[0];
        float bh = best ? phv[1] : phv[0];
        float dw = sqrtf(fmaxf(bw, eps)) - sqrtf(fmaxf(tw, eps));
        float dh = sqrtf(fmaxf(bh, eps)) - sqrtf(fmaxf(th, eps));
        float box_l = dx * dx + dy * dy + dw * dw + dh * dh;
        float obj_l = (cfm - 1.0f) * (cfm - 1.0f);

        // class loss via sum-of-squares identity: one reciprocal, no ev[] array
        const float* cl = cell + 10;
        float m = cl[0];
        #pragma unroll
        for (int c = 1; c < Cnum; ++c) m = fmaxf(m, cl[c]);
        float esum = 0.0f, e2 = 0.0f, elab = 0.0f;
        #pragma unroll
        for (int c = 0; c < Cnum; ++c) {
            float e = __expf(cl[c] - m);
            esum += e; e2 += e * e;
            if (c == lab) elab = e;
        }
        float inv = 1.0f / esum;
        float cls_l = e2 * inv * inv - 2.0f * elab * inv + 1.0f;

        float tl = LCf * box_l + obj_l + cls_l;

        // 16-lane group reduce (per image)
        #pragma unroll
        for (int off = 1; off < 16; off <<= 1) {
            tl   += __shfl_xor(tl, off);
            msum += __shfl_xor(msum, off);
            mcnt += __shfl_xor(mcnt, off);
        }
        if (myidx == 0) {
            s_tri[img][0] = tl;
            s_tri[img][1] = msum;
            s_tri[img][2] = mcnt;
        }
    }
    __syncthreads();

    if (lane == 0) {
        float tl   = s_tri[wave][0];
        float msum = s_tri[wave][1];
        float mcnt = s_tri[wave][2];
        s_pb[wave] = tl + LNf * (ns - msum) / (98.0f - mcnt);
    }
    __syncthreads();
    if (tid == 0)
        block_sum[blockIdx.x] = (s_pb[0] + s_pb[1]) + (s_pb[2] + s_pb[3]);
}

__global__ __launch_bounds__(256) void reduce_mean_kernel(
    const float* __restrict__ block_sum, float* __restrict__ out, int nb, int N)
{
    __shared__ double sd[4];
    double acc = 0.0;
    const float4* p4 = reinterpret_cast<const float4*>(block_sum);
    for (int i = threadIdx.x; i < nb / 4; i += 256) {
        float4 v = p4[i];
        acc += (double)v.x + (double)v.y + (double)v.z + (double)v.w;
    }
    #pragma unroll
    for (int off = 32; off > 0; off >>= 1) acc += __shfl_xor(acc, off);
    if ((threadIdx.x & 63) == 0) sd[threadIdx.x >> 6] = acc;
    __syncthreads();
    if (threadIdx.x == 0)
        out[0] = (float)(((sd[0] + sd[1]) + (sd[2] + sd[3])) / (double)N);
}

extern "C" void kernel_launch(void* const* d_in, const int* in_sizes, int n_in,
                              void* d_out, int out_size, void* d_ws, size_t ws_size,
                              hipStream_t stream) {
    const float* outputs = (const float*)d_in[0];
    const float* boxes   = (const float*)d_in[1];
    const int*   labels  = (const int*)d_in[2];
    float* out = (float*)d_out;

    const int N  = in_sizes[0] / IMGF;  // 16384
    const int nb = N / IPB;             // 4096 blocks
    float* block_sum = (float*)d_ws;

    yolo_loss_kernel<<<nb, 256, 0, stream>>>(outputs, boxes, labels, block_sum);
    reduce_mean_kernel<<<1, 256, 0, stream>>>(block_sum, out, nb, N);
}